// Round 15
// baseline (117.797 us; speedup 1.0000x reference)
//
#include <hip/hip_runtime.h>
#include <hip/hip_bf16.h>
#include <string.h>

#define NTOK 64
#define HEADS 8
#define SKV 136   // stage row stride (ushorts) = 272 B
#define SO  132   // O-stage row stride (floats) = 528 B -> 2-way-free banks

typedef __attribute__((ext_vector_type(4))) float f32x4;
typedef __attribute__((ext_vector_type(2))) unsigned int u32x2;
typedef __attribute__((ext_vector_type(8))) short bf16x8;

// packed f32x2 -> bf16x2 (RNE) -- v_cvt_pk_bf16_f32
__device__ __forceinline__ unsigned int cvt2(float a, float b) {
    __hip_bfloat162 h = __float22bfloat162_rn(float2{a, b});
    unsigned int r;
    memcpy(&r, &h, 4);
    return r;
}

// Fused prelude: one block per relative position (225). Computes the 2->256->8
// MLP for its (dy,dx), then scatters log2e*bias directly into the fragment-layout
// table bias_ws[h][mt][nt][lane][r] for every (n,m) with that offset.
__global__ __launch_bounds__(64) void mlp_bias_kernel(
    const float* __restrict__ w1, const float* __restrict__ b1,
    const float* __restrict__ w2, const float* __restrict__ b2,
    float* __restrict__ bias_ws)
{
    int pair = blockIdx.x;
    int lane = threadIdx.x;
    int dy = pair / 15 - 7;
    int dx = pair % 15 - 7;
    float fy = copysignf(log1pf(fabsf((float)dy)), (float)dy);
    float fx = copysignf(log1pf(fabsf((float)dx)), (float)dx);
    int h = lane & 7;
    int j0 = lane >> 3;
    float acc = 0.0f;
    #pragma unroll 4
    for (int i = 0; i < 32; ++i) {
        int j = j0 + 8 * i;
        float t = fy * w1[j] + fx * w1[256 + j] + b1[j];
        float ge = 0.5f * t * (1.0f + erff(t * 0.70710678118654752f)); // exact GELU
        acc = fmaf(ge, w2[j * HEADS + h], acc);
    }
    acc += __shfl_xor(acc, 8, 64);
    acc += __shfl_xor(acc, 16, 64);
    acc += __shfl_xor(acc, 32, 64);
    float val = (acc + b2[h]) * 1.44269504088896341f;   // fold log2(e)

    int ny0 = dy > 0 ? dy : 0;
    int nx0 = dx > 0 ? dx : 0;
    int cnty = 8 - (dy < 0 ? -dy : dy);
    int cntx = 8 - (dx < 0 ? -dx : dx);
    for (int iy = 0; iy < cnty; ++iy) {
        int ny = ny0 + iy, my = ny - dy;
        for (int ix = (lane >> 3); ix < cntx; ix += 8) {
            int nx = nx0 + ix, mx = nx - dx;
            int n = ny * 8 + nx;
            int m = my * 8 + mx;
            int nt = n >> 4, mt = m >> 4;
            int l = ((m >> 2) & 3) * 16 + (n & 15);
            int r = m & 3;
            bias_ws[(((h * 4 + mt) * 4 + nt) * 64 + l) * 4 + r] = val;
        }
    }
}

// Persistent version: grid = 768 (256 CU x 3 resident), each block grid-strides
// over the 2B work items. Per item: K,V coop-staged (512-B nt segments), Q direct
// nt + per-strip prefetch, O staged in LDS f32, coop nt store.
__global__ __launch_bounds__(256, 4) void win_attn_kernel(
    const float* __restrict__ qkv,
    const float* __restrict__ bias_ws,
    float* __restrict__ out,
    int nwork)
{
    // layout: [0, 17408) K stage | [17408, 34816) V stage | [34816, 53248) P dbuf
    //         O stage f32 [64][SO] (33792 B) overlays K+V after frags are register-resident
    __shared__ __align__(16) unsigned char lds_all[53248];
    unsigned short* lds_k = (unsigned short*)lds_all;
    unsigned short* lds_v = (unsigned short*)(lds_all + 17408);
    unsigned short (*lds_p)[16][72] = (unsigned short (*)[16][72])(lds_all + 34816 + (threadIdx.x >> 6) * 4608);
    float* ostage = (float*)lds_all;

    const int tid = threadIdx.x;
    const int w = tid >> 6;
    const int l = tid & 63;
    const int c = l & 15;
    const int g = l >> 4;
    const float QS = 0.176776695296636893f * 1.44269504088896341f; // scale * log2(e)

    for (int it = blockIdx.x; it < nwork; it += gridDim.x) {
        const int half = it & 1;
        const int b = it >> 1;
        const int h = half * 4 + w;                      // this wave's head
        const float* wbase = qkv + (size_t)b * (NTOK * 768);

        // ---- block-cooperative staging of K,V (bf16), nontemporal loads ----
        {
            const int srow0 = tid >> 5;
            const int scol  = (tid & 31) * 4;
            #pragma unroll
            for (int i = 0; i < 8; ++i) {
                int row = i * 8 + srow0;
                const float* pr = wbase + (size_t)row * 768 + half * 128 + scol;
                f32x4 kk = __builtin_nontemporal_load((const f32x4*)(pr + 256));
                f32x4 vv = __builtin_nontemporal_load((const f32x4*)(pr + 512));
                u32x2 kw = {cvt2(kk[0], kk[1]), cvt2(kk[2], kk[3])};
                u32x2 vw = {cvt2(vv[0], vv[1]), cvt2(vv[2], vv[3])};
                *(u32x2*)(lds_k + row * SKV + scol) = kw;
                *(u32x2*)(lds_v + row * SKV + scol) = vw;
            }
        }
        __syncthreads();

        // ---- K A-frags from LDS (b128) ----
        bf16x8 kf[4];
        #pragma unroll
        for (int t = 0; t < 4; ++t)
            kf[t] = *(const bf16x8*)(lds_k + (t * 16 + c) * SKV + w * 32 + g * 8);

        // ---- V^T A-frags: column reads (u16, once per wave) ----
        bf16x8 vf[2][2];
        #pragma unroll
        for (int ks = 0; ks < 2; ++ks)
            #pragma unroll
            for (int dt = 0; dt < 2; ++dt) {
                bf16x8 v;
                #pragma unroll
                for (int j = 0; j < 8; ++j)
                    v[j] = (short)lds_v[(ks * 32 + g * 8 + j) * SKV + w * 32 + dt * 16 + c];
                vf[ks][dt] = v;
            }
        __syncthreads();   // K/V region now dead -> safe to overlay with O stage

        // Q strip 0 raw (direct nontemporal; per-strip prefetch below)
        const float* qb = wbase + h * 32;
        f32x4 qraw0, qraw1;
        {
            const float* pq = qb + (size_t)c * 768 + g * 8;
            qraw0 = __builtin_nontemporal_load((const f32x4*)(pq));
            qraw1 = __builtin_nontemporal_load((const f32x4*)(pq + 4));
        }

        // ---- strip loop over n (nt): S^T strip -> exp2 -> P -> O^T strip -> LDS O-stage ----
        #pragma unroll
        for (int nt = 0; nt < 4; ++nt) {
            bf16x8 qf;
            {
                unsigned int qq[4] = {cvt2(qraw0[0] * QS, qraw0[1] * QS),
                                      cvt2(qraw0[2] * QS, qraw0[3] * QS),
                                      cvt2(qraw1[0] * QS, qraw1[1] * QS),
                                      cvt2(qraw1[2] * QS, qraw1[3] * QS)};
                memcpy(&qf, qq, 16);
            }

            // S^T strip = K.Q^T seeded with bias frags (C-operand; L2-resident table)
            f32x4 acc[4];
            {
                const f32x4* bw = (const f32x4*)(bias_ws) + ((size_t)h * 16 + nt) * 64 + l;
                #pragma unroll
                for (int mt = 0; mt < 4; ++mt)
                    acc[mt] = bw[mt * 256];
            }
            #pragma unroll
            for (int mt = 0; mt < 4; ++mt)
                acc[mt] = __builtin_amdgcn_mfma_f32_16x16x32_bf16(kf[mt], qf, acc[mt], 0, 0, 0);

            // prefetch next strip's Q while MFMAs run
            if (nt < 3) {
                const float* pq = qb + (size_t)((nt + 1) * 16 + c) * 768 + g * 8;
                qraw0 = __builtin_nontemporal_load((const f32x4*)(pq));
                qraw1 = __builtin_nontemporal_load((const f32x4*)(pq + 4));
            }

            // softmax numerators, no max-subtract (bounded log2-unit scores; f32-safe)
            float s = 0.0f;
            #pragma unroll
            for (int mt = 0; mt < 4; ++mt)
                #pragma unroll
                for (int r = 0; r < 4; ++r) {
                    float p = __builtin_amdgcn_exp2f(acc[mt][r]);
                    acc[mt][r] = p;
                    s += p;
                }

            // P strip (bf16, [n][m]) -> LDS (packed cvt + b64 writes, double-buffered)
            unsigned short (*P)[72] = lds_p[nt & 1];
            #pragma unroll
            for (int mt = 0; mt < 4; ++mt) {
                unsigned int w0 = cvt2(acc[mt][0], acc[mt][1]);
                unsigned int w1 = cvt2(acc[mt][2], acc[mt][3]);
                *(u32x2*)(&P[c][mt * 16 + g * 4]) = (u32x2){w0, w1};
            }

            // cross-lane sum finish + rcp (overlaps the fence drain)
            s += __shfl_xor(s, 16, 64);
            s += __shfl_xor(s, 32, 64);
            float iv = __builtin_amdgcn_rcpf(s);

            // order: P ds_writes visible before cross-lane ds_reads
            __threadfence_block();

            // O^T strip = V^T . P^T
            f32x4 o[2];
            o[0] = (f32x4){0.f, 0.f, 0.f, 0.f};
            o[1] = (f32x4){0.f, 0.f, 0.f, 0.f};
            #pragma unroll
            for (int ks = 0; ks < 2; ++ks) {
                bf16x8 pb = *(const bf16x8*)(&P[c][ks * 32 + g * 8]);
                #pragma unroll
                for (int dt = 0; dt < 2; ++dt)
                    o[dt] = __builtin_amdgcn_mfma_f32_16x16x32_bf16(vf[ks][dt], pb, o[dt], 0, 0, 0);
            }

            // normalize + write to LDS O-stage [64][SO] f32 (col ranges disjoint per wave)
            #pragma unroll
            for (int dt = 0; dt < 2; ++dt) {
                f32x4 val;
                #pragma unroll
                for (int r = 0; r < 4; ++r)
                    val[r] = o[dt][r] * iv;
                *(f32x4*)(ostage + (nt * 16 + c) * SO + w * 32 + dt * 16 + g * 4) = val;
            }
        }
        __syncthreads();

        // ---- block-cooperative store: nontemporal, 512-B contiguous per wave-instr ----
        {
            float* ob = out + (size_t)b * (NTOK * 256) + half * 128;
            const int srow0 = tid >> 5;
            const int scol  = (tid & 31) * 4;
            #pragma unroll
            for (int i = 0; i < 8; ++i) {
                int row = i * 8 + srow0;
                f32x4 val = *(const f32x4*)(ostage + row * SO + scol);
                __builtin_nontemporal_store(val, (f32x4*)(ob + (size_t)row * 256 + scol));
            }
        }
        __syncthreads();   // ostage fully consumed before next iteration's K/V stage overlays it
    }
}

extern "C" void kernel_launch(void* const* d_in, const int* in_sizes, int n_in,
                              void* d_out, int out_size, void* d_ws, size_t ws_size,
                              hipStream_t stream) {
    const float* qkv = (const float*)d_in[0];
    const float* w1  = (const float*)d_in[1];
    const float* b1  = (const float*)d_in[2];
    const float* w2  = (const float*)d_in[3];
    const float* b2  = (const float*)d_in[4];
    float* bias_ws = (float*)d_ws;   // 32768 floats = 128 KiB (proven size)

    mlp_bias_kernel<<<225, 64, 0, stream>>>(w1, b1, w2, b2, bias_ws);

    int B = in_sizes[0] / 49152;   // windows
    int nwork = B * 2;
    int grid = nwork < 768 ? nwork : 768;   // 256 CU x 3 resident blocks
    win_attn_kernel<<<grid, 256, 0, stream>>>(qkv, bias_ws, (float*)d_out, nwork);
}

// Round 16
// 109.632 us; speedup vs baseline: 1.0745x; 1.0745x over previous
//
#include <hip/hip_runtime.h>
#include <hip/hip_bf16.h>
#include <string.h>

#define NTOK 64
#define HEADS 8
#define SKV 136   // stage row stride (ushorts) = 272 B
#define SO  132   // O-stage row stride (floats) = 528 B -> 2-way-free banks

typedef __attribute__((ext_vector_type(4))) float f32x4;
typedef __attribute__((ext_vector_type(2))) unsigned int u32x2;
typedef __attribute__((ext_vector_type(8))) short bf16x8;

// packed f32x2 -> bf16x2 (RNE) -- v_cvt_pk_bf16_f32
__device__ __forceinline__ unsigned int cvt2(float a, float b) {
    __hip_bfloat162 h = __float22bfloat162_rn(float2{a, b});
    unsigned int r;
    memcpy(&r, &h, 4);
    return r;
}

// Fused prelude: one block per relative position (225). Computes the 2->256->8
// MLP for its (dy,dx), then scatters log2e*bias directly into the fragment-layout
// table bias_ws[h][mt][nt][lane][r] for every (n,m) with that offset.
__global__ __launch_bounds__(64) void mlp_bias_kernel(
    const float* __restrict__ w1, const float* __restrict__ b1,
    const float* __restrict__ w2, const float* __restrict__ b2,
    float* __restrict__ bias_ws)
{
    int pair = blockIdx.x;
    int lane = threadIdx.x;
    int dy = pair / 15 - 7;
    int dx = pair % 15 - 7;
    float fy = copysignf(log1pf(fabsf((float)dy)), (float)dy);
    float fx = copysignf(log1pf(fabsf((float)dx)), (float)dx);
    int h = lane & 7;
    int j0 = lane >> 3;
    float acc = 0.0f;
    #pragma unroll 4
    for (int i = 0; i < 32; ++i) {
        int j = j0 + 8 * i;
        float t = fy * w1[j] + fx * w1[256 + j] + b1[j];
        float ge = 0.5f * t * (1.0f + erff(t * 0.70710678118654752f)); // exact GELU
        acc = fmaf(ge, w2[j * HEADS + h], acc);
    }
    acc += __shfl_xor(acc, 8, 64);
    acc += __shfl_xor(acc, 16, 64);
    acc += __shfl_xor(acc, 32, 64);
    float val = (acc + b2[h]) * 1.44269504088896341f;   // fold log2(e)

    int ny0 = dy > 0 ? dy : 0;
    int nx0 = dx > 0 ? dx : 0;
    int cnty = 8 - (dy < 0 ? -dy : dy);
    int cntx = 8 - (dx < 0 ? -dx : dx);
    for (int iy = 0; iy < cnty; ++iy) {
        int ny = ny0 + iy, my = ny - dy;
        for (int ix = (lane >> 3); ix < cntx; ix += 8) {
            int nx = nx0 + ix, mx = nx - dx;
            int n = ny * 8 + nx;
            int m = my * 8 + mx;
            int nt = n >> 4, mt = m >> 4;
            int l = ((m >> 2) & 3) * 16 + (n & 15);
            int r = m & 3;
            bias_ws[(((h * 4 + mt) * 4 + nt) * 64 + l) * 4 + r] = val;
        }
    }
}

// Block = 4 heads of one window. K,V staged block-cooperatively (512-B segments);
// Q direct + per-strip prefetch; O staged in LDS f32 and stored block-cooperatively.
// ALL HBM traffic nontemporal (zero-reuse streams).  [proven best: 109.5 us]
__global__ __launch_bounds__(256, 4) void win_attn_kernel(
    const float* __restrict__ qkv,
    const float* __restrict__ bias_ws,
    float* __restrict__ out)
{
    // layout: [0, 17408) K stage | [17408, 34816) V stage | [34816, 53248) P dbuf
    //         O stage f32 [64][SO] (33792 B) overlays K+V after frags are register-resident
    __shared__ __align__(16) unsigned char lds_all[53248];
    unsigned short* lds_k = (unsigned short*)lds_all;
    unsigned short* lds_v = (unsigned short*)(lds_all + 17408);
    unsigned short (*lds_p)[16][72] = (unsigned short (*)[16][72])(lds_all + 34816 + (threadIdx.x >> 6) * 4608);
    float* ostage = (float*)lds_all;

    const int tid = threadIdx.x;
    const int w = tid >> 6;
    const int l = tid & 63;
    const int c = l & 15;
    const int g = l >> 4;
    const int half = blockIdx.x & 1;
    const int b = blockIdx.x >> 1;
    const int h = half * 4 + w;                      // this wave's head
    const float* wbase = qkv + (size_t)b * (NTOK * 768);
    const float QS = 0.176776695296636893f * 1.44269504088896341f; // scale * log2(e)

    // ---- block-cooperative staging of K,V (bf16), nontemporal loads ----
    {
        const int srow0 = tid >> 5;
        const int scol  = (tid & 31) * 4;
        #pragma unroll
        for (int i = 0; i < 8; ++i) {
            int row = i * 8 + srow0;
            const float* pr = wbase + (size_t)row * 768 + half * 128 + scol;
            f32x4 kk = __builtin_nontemporal_load((const f32x4*)(pr + 256));
            f32x4 vv = __builtin_nontemporal_load((const f32x4*)(pr + 512));
            u32x2 kw = {cvt2(kk[0], kk[1]), cvt2(kk[2], kk[3])};
            u32x2 vw = {cvt2(vv[0], vv[1]), cvt2(vv[2], vv[3])};
            *(u32x2*)(lds_k + row * SKV + scol) = kw;
            *(u32x2*)(lds_v + row * SKV + scol) = vw;
        }
    }
    __syncthreads();

    // ---- K A-frags from LDS (b128) ----
    bf16x8 kf[4];
    #pragma unroll
    for (int t = 0; t < 4; ++t)
        kf[t] = *(const bf16x8*)(lds_k + (t * 16 + c) * SKV + w * 32 + g * 8);

    // ---- V^T A-frags: column reads (u16, once per wave) ----
    bf16x8 vf[2][2];
    #pragma unroll
    for (int ks = 0; ks < 2; ++ks)
        #pragma unroll
        for (int dt = 0; dt < 2; ++dt) {
            bf16x8 v;
            #pragma unroll
            for (int j = 0; j < 8; ++j)
                v[j] = (short)lds_v[(ks * 32 + g * 8 + j) * SKV + w * 32 + dt * 16 + c];
            vf[ks][dt] = v;
        }
    __syncthreads();   // K/V region now dead -> safe to overlay with O stage

    // Q strip 0 raw (direct nontemporal; per-strip prefetch below)
    const float* qb = wbase + h * 32;
    f32x4 qraw0, qraw1;
    {
        const float* pq = qb + (size_t)c * 768 + g * 8;
        qraw0 = __builtin_nontemporal_load((const f32x4*)(pq));
        qraw1 = __builtin_nontemporal_load((const f32x4*)(pq + 4));
    }

    // ---- strip loop over n (nt): S^T strip -> exp2 -> P -> O^T strip -> LDS O-stage ----
    #pragma unroll
    for (int nt = 0; nt < 4; ++nt) {
        bf16x8 qf;
        {
            unsigned int qq[4] = {cvt2(qraw0[0] * QS, qraw0[1] * QS),
                                  cvt2(qraw0[2] * QS, qraw0[3] * QS),
                                  cvt2(qraw1[0] * QS, qraw1[1] * QS),
                                  cvt2(qraw1[2] * QS, qraw1[3] * QS)};
            memcpy(&qf, qq, 16);
        }

        // S^T strip = K.Q^T seeded with bias frags (C-operand; L2-resident table)
        f32x4 acc[4];
        {
            const f32x4* bw = (const f32x4*)(bias_ws) + ((size_t)h * 16 + nt) * 64 + l;
            #pragma unroll
            for (int mt = 0; mt < 4; ++mt)
                acc[mt] = bw[mt * 256];
        }
        #pragma unroll
        for (int mt = 0; mt < 4; ++mt)
            acc[mt] = __builtin_amdgcn_mfma_f32_16x16x32_bf16(kf[mt], qf, acc[mt], 0, 0, 0);

        // prefetch next strip's Q while MFMAs run
        if (nt < 3) {
            const float* pq = qb + (size_t)((nt + 1) * 16 + c) * 768 + g * 8;
            qraw0 = __builtin_nontemporal_load((const f32x4*)(pq));
            qraw1 = __builtin_nontemporal_load((const f32x4*)(pq + 4));
        }

        // softmax numerators, no max-subtract (bounded log2-unit scores; f32-safe)
        float s = 0.0f;
        #pragma unroll
        for (int mt = 0; mt < 4; ++mt)
            #pragma unroll
            for (int r = 0; r < 4; ++r) {
                float p = __builtin_amdgcn_exp2f(acc[mt][r]);
                acc[mt][r] = p;
                s += p;
            }

        // P strip (bf16, [n][m]) -> LDS (packed cvt + b64 writes, double-buffered)
        unsigned short (*P)[72] = lds_p[nt & 1];
        #pragma unroll
        for (int mt = 0; mt < 4; ++mt) {
            unsigned int w0 = cvt2(acc[mt][0], acc[mt][1]);
            unsigned int w1 = cvt2(acc[mt][2], acc[mt][3]);
            *(u32x2*)(&P[c][mt * 16 + g * 4]) = (u32x2){w0, w1};
        }

        // cross-lane sum finish + rcp (overlaps the fence drain)
        s += __shfl_xor(s, 16, 64);
        s += __shfl_xor(s, 32, 64);
        float iv = __builtin_amdgcn_rcpf(s);

        // order: P ds_writes visible before cross-lane ds_reads
        __threadfence_block();

        // O^T strip = V^T . P^T
        f32x4 o[2];
        o[0] = (f32x4){0.f, 0.f, 0.f, 0.f};
        o[1] = (f32x4){0.f, 0.f, 0.f, 0.f};
        #pragma unroll
        for (int ks = 0; ks < 2; ++ks) {
            bf16x8 pb = *(const bf16x8*)(&P[c][ks * 32 + g * 8]);
            #pragma unroll
            for (int dt = 0; dt < 2; ++dt)
                o[dt] = __builtin_amdgcn_mfma_f32_16x16x32_bf16(vf[ks][dt], pb, o[dt], 0, 0, 0);
        }

        // normalize + write to LDS O-stage [64][SO] f32 (col ranges disjoint per wave)
        #pragma unroll
        for (int dt = 0; dt < 2; ++dt) {
            f32x4 val;
            #pragma unroll
            for (int r = 0; r < 4; ++r)
                val[r] = o[dt][r] * iv;
            *(f32x4*)(ostage + (nt * 16 + c) * SO + w * 32 + dt * 16 + g * 4) = val;
        }
    }
    __syncthreads();

    // ---- block-cooperative store: nontemporal, 512-B contiguous per wave-instr ----
    {
        float* ob = out + (size_t)b * (NTOK * 256) + half * 128;
        const int srow0 = tid >> 5;
        const int scol  = (tid & 31) * 4;
        #pragma unroll
        for (int i = 0; i < 8; ++i) {
            int row = i * 8 + srow0;
            f32x4 val = *(const f32x4*)(ostage + row * SO + scol);
            __builtin_nontemporal_store(val, (f32x4*)(ob + (size_t)row * 256 + scol));
        }
    }
}

extern "C" void kernel_launch(void* const* d_in, const int* in_sizes, int n_in,
                              void* d_out, int out_size, void* d_ws, size_t ws_size,
                              hipStream_t stream) {
    const float* qkv = (const float*)d_in[0];
    const float* w1  = (const float*)d_in[1];
    const float* b1  = (const float*)d_in[2];
    const float* w2  = (const float*)d_in[3];
    const float* b2  = (const float*)d_in[4];
    float* bias_ws = (float*)d_ws;   // 32768 floats = 128 KiB (proven size)

    mlp_bias_kernel<<<225, 64, 0, stream>>>(w1, b1, w2, b2, bias_ws);

    int B = in_sizes[0] / 49152;   // windows
    win_attn_kernel<<<B * 2, 256, 0, stream>>>(qkv, bias_ws, (float*)d_out);
}